// Round 1
// baseline (137.604 us; speedup 1.0000x reference)
//
#include <hip/hip_runtime.h>
#include <hip/hip_bf16.h>
#include <math.h>

#define STU_NUM   100000
#define PROB_NUM  20000
#define KNOW_NUM  128
#define DIM       128
#define BATCH     8192
#define HIDDEN    512

__device__ __forceinline__ float sigmoidf_(float x) {
    return 1.0f / (1.0f + __expf(-x));
}

// KT[d][k] = z[(STU_NUM+PROB_NUM+k)*DIM + d]   (transpose of knowledge block)
__global__ void kt_kernel(const float* __restrict__ z, float* __restrict__ KT) {
    int i = blockIdx.x * 256 + threadIdx.x;  // 16384 elements
    if (i < KNOW_NUM * DIM) {
        int k = i >> 7, d = i & 127;
        KT[d * KNOW_NUM + k] = z[(size_t)(STU_NUM + PROB_NUM + k) * DIM + d];
    }
}

// Generic f32 tiled GEMM: C[M][N] = act(A[M][K] @ B[K][N] + bias)
// BM=128, BN=64, BK=64; 256 threads; per-thread 8x4 micro-tile.
// GATHER variant: A row r (<BATCH) = z[sid[r]] * w_stat; row r>=BATCH = z[eid[r-BATCH]] * w_kdiff.
template<bool GATHER, int ACT, bool HAS_BIAS>
__global__ __launch_bounds__(256, 2) void gemm_kernel(
    const float* __restrict__ A, const float* __restrict__ B,
    const float* __restrict__ bias, float* __restrict__ C,
    int M, int N, int K,
    const int* __restrict__ sid, const int* __restrict__ eid,
    const float* __restrict__ w_stat, const float* __restrict__ w_kdiff,
    const float* __restrict__ z) {
    __shared__ float As[128 * 68];   // [m][k], pad 64->68 to break bank alignment
    __shared__ float Bs[64 * 64];    // [k][n]
    const int t  = threadIdx.x;
    const int m0 = blockIdx.x * 128;
    const int n0 = blockIdx.y * 64;
    const int tx = t & 15;           // n-thread (4 cols each)
    const int ty = t >> 4;           // m-thread (8 rows each)

    float acc[8][4] = {};

    for (int k0 = 0; k0 < K; k0 += 64) {
        __syncthreads();
        // --- A tile: 128 rows x 64 k-cols = 2048 float4, 8 per thread (coalesced) ---
        #pragma unroll
        for (int i = 0; i < 8; ++i) {
            int p   = i * 256 + t;
            int row = p >> 4;
            int c4  = (p & 15) * 4;
            float4 v;
            if constexpr (GATHER) {
                int gr = m0 + row;
                int zrow;
                const float* wv;
                if (gr < BATCH) { zrow = sid[gr];          wv = w_stat;  }
                else            { zrow = eid[gr - BATCH];  wv = w_kdiff; }
                float4 zv  = *reinterpret_cast<const float4*>(z  + (size_t)zrow * DIM + k0 + c4);
                float4 wv4 = *reinterpret_cast<const float4*>(wv + k0 + c4);
                v = make_float4(zv.x * wv4.x, zv.y * wv4.y, zv.z * wv4.z, zv.w * wv4.w);
            } else {
                v = *reinterpret_cast<const float4*>(A + (size_t)(m0 + row) * K + k0 + c4);
            }
            *reinterpret_cast<float4*>(&As[row * 68 + c4]) = v;
        }
        // --- B tile: 64 k-rows x 64 n-cols = 1024 float4, 4 per thread (coalesced) ---
        #pragma unroll
        for (int i = 0; i < 4; ++i) {
            int p   = i * 256 + t;
            int row = p >> 4;
            int c4  = (p & 15) * 4;
            float4 v = *reinterpret_cast<const float4*>(B + (size_t)(k0 + row) * N + n0 + c4);
            *reinterpret_cast<float4*>(&Bs[row * 64 + c4]) = v;
        }
        __syncthreads();
        // --- inner product ---
        #pragma unroll 8
        for (int kk = 0; kk < 64; ++kk) {
            float4 b = *reinterpret_cast<const float4*>(&Bs[kk * 64 + tx * 4]);
            float a[8];
            #pragma unroll
            for (int i = 0; i < 8; ++i) a[i] = As[(ty * 8 + i) * 68 + kk];
            #pragma unroll
            for (int i = 0; i < 8; ++i) {
                acc[i][0] = fmaf(a[i], b.x, acc[i][0]);
                acc[i][1] = fmaf(a[i], b.y, acc[i][1]);
                acc[i][2] = fmaf(a[i], b.z, acc[i][2]);
                acc[i][3] = fmaf(a[i], b.w, acc[i][3]);
            }
        }
    }

    // --- epilogue: bias + activation + coalesced store ---
    float4 bv = make_float4(0.f, 0.f, 0.f, 0.f);
    if constexpr (HAS_BIAS) {
        bv = *reinterpret_cast<const float4*>(bias + n0 + tx * 4);
    }
    #pragma unroll
    for (int i = 0; i < 8; ++i) {
        float4 o;
        o.x = acc[i][0] + bv.x;
        o.y = acc[i][1] + bv.y;
        o.z = acc[i][2] + bv.z;
        o.w = acc[i][3] + bv.w;
        if constexpr (ACT == 1) {
            o.x = tanhf(o.x); o.y = tanhf(o.y); o.z = tanhf(o.z); o.w = tanhf(o.w);
        }
        *reinterpret_cast<float4*>(C + (size_t)(m0 + ty * 8 + i) * N + n0 + tx * 4) = o;
    }
}

// state = kp * (sigmoid(C1_top + b_stat) - sigmoid(C1_bot + b_kdiff)), float4-vectorized
__global__ void combine_kernel(const float* __restrict__ C1, const float* __restrict__ kp,
                               const float* __restrict__ bstat, const float* __restrict__ bkdiff,
                               float* __restrict__ state) {
    int i = blockIdx.x * 256 + threadIdx.x;  // over BATCH*KNOW_NUM/4
    if (i < BATCH * KNOW_NUM / 4) {
        float bs = bstat[0], bk = bkdiff[0];
        float4 c1  = reinterpret_cast<const float4*>(C1)[i];
        float4 c2  = reinterpret_cast<const float4*>(C1 + (size_t)BATCH * KNOW_NUM)[i];
        float4 kpv = reinterpret_cast<const float4*>(kp)[i];
        float4 o;
        o.x = kpv.x * (sigmoidf_(c1.x + bs) - sigmoidf_(c2.x + bk));
        o.y = kpv.y * (sigmoidf_(c1.y + bs) - sigmoidf_(c2.y + bk));
        o.z = kpv.z * (sigmoidf_(c1.z + bs) - sigmoidf_(c2.z + bk));
        o.w = kpv.w * (sigmoidf_(c1.w + bs) - sigmoidf_(c2.w + bk));
        reinterpret_cast<float4*>(state)[i] = o;
    }
}

// out[b] = sigmoid(dot(h3[b], W4) + b4)
__global__ void final_kernel(const float* __restrict__ h3, const float* __restrict__ W4,
                             const float* __restrict__ b4, float* __restrict__ out) {
    int b = blockIdx.x * 256 + threadIdx.x;
    if (b < BATCH) {
        const float4* row = reinterpret_cast<const float4*>(h3 + (size_t)b * (HIDDEN / 4));
        const float4* w   = reinterpret_cast<const float4*>(W4);
        float s = 0.f;
        #pragma unroll
        for (int j = 0; j < HIDDEN / 16; ++j) {   // 128/4 = 32 float4s
            float4 v = row[j];
            float4 ww = w[j];
            s += v.x * ww.x + v.y * ww.y + v.z * ww.z + v.w * ww.w;
        }
        out[b] = sigmoidf_(s + b4[0]);
    }
}

extern "C" void kernel_launch(void* const* d_in, const int* in_sizes, int n_in,
                              void* d_out, int out_size, void* d_ws, size_t ws_size,
                              hipStream_t stream) {
    const float* z       = (const float*)d_in[0];
    const int*   sid     = (const int*)d_in[1];
    const int*   eid     = (const int*)d_in[2];
    const float* kp      = (const float*)d_in[3];
    const float* w_stat  = (const float*)d_in[4];
    const float* b_stat  = (const float*)d_in[5];
    const float* w_kdiff = (const float*)d_in[6];
    const float* b_kdiff = (const float*)d_in[7];
    const float* W1      = (const float*)d_in[8];
    const float* b1      = (const float*)d_in[9];
    const float* W2      = (const float*)d_in[10];
    const float* b2      = (const float*)d_in[11];
    const float* W3      = (const float*)d_in[12];
    const float* b3      = (const float*)d_in[13];
    const float* W4      = (const float*)d_in[14];
    const float* b4      = (const float*)d_in[15];
    float* out = (float*)d_out;

    // Workspace layout (bytes). Peak use ~29.4 MB.
    char* ws = (char*)d_ws;
    float* KT    = (float*)(ws);                                   // 64 KB
    float* C1    = (float*)(ws + (1 << 16));                       // 16384*128*4 = 8 MB
    float* state = (float*)(ws + (1 << 16) + (8  << 20));          // 4 MB
    float* h1    = (float*)(ws + (1 << 16) + (12 << 20));          // 16 MB
    float* h2    = C1;     // C1 dead after combine
    float* h3    = state;  // state dead after h1 GEMM

    // 1) knowledge transpose
    hipLaunchKernelGGL(kt_kernel, dim3(64), dim3(256), 0, stream, z, KT);

    // 2) fused gather+scale GEMM: C1[16384][128] = [XS;XK] @ KT
    hipLaunchKernelGGL((gemm_kernel<true, 0, false>), dim3(2 * BATCH / 128, KNOW_NUM / 64), dim3(256), 0, stream,
                       nullptr, KT, nullptr, C1, 2 * BATCH, KNOW_NUM, DIM,
                       sid, eid, w_stat, w_kdiff, z);

    // 3) state = kp * (sig - sig)
    hipLaunchKernelGGL(combine_kernel, dim3(BATCH * KNOW_NUM / 4 / 256), dim3(256), 0, stream,
                       C1, kp, b_stat, b_kdiff, state);

    // 4) h1 = tanh(state @ W1 + b1)   [8192 x 512], K=128
    hipLaunchKernelGGL((gemm_kernel<false, 1, true>), dim3(BATCH / 128, HIDDEN / 64), dim3(256), 0, stream,
                       state, W1, b1, h1, BATCH, HIDDEN, KNOW_NUM,
                       nullptr, nullptr, nullptr, nullptr, nullptr);

    // 5) h2 = tanh(h1 @ W2 + b2)      [8192 x 256], K=512
    hipLaunchKernelGGL((gemm_kernel<false, 1, true>), dim3(BATCH / 128, (HIDDEN / 2) / 64), dim3(256), 0, stream,
                       h1, W2, b2, h2, BATCH, HIDDEN / 2, HIDDEN,
                       nullptr, nullptr, nullptr, nullptr, nullptr);

    // 6) h3 = tanh(h2 @ W3 + b3)      [8192 x 128], K=256
    hipLaunchKernelGGL((gemm_kernel<false, 1, true>), dim3(BATCH / 128, (HIDDEN / 4) / 64), dim3(256), 0, stream,
                       h2, W3, b3, h3, BATCH, HIDDEN / 4, HIDDEN / 2,
                       nullptr, nullptr, nullptr, nullptr, nullptr);

    // 7) out = sigmoid(h3 @ W4 + b4)
    hipLaunchKernelGGL(final_kernel, dim3(BATCH / 256), dim3(256), 0, stream, h3, W4, b4, out);
}

// Round 2
// 39.548 us; speedup vs baseline: 3.4794x; 3.4794x over previous
//
#include <hip/hip_runtime.h>
#include <hip/hip_bf16.h>
#include <math.h>

#define STU_NUM   100000
#define PROB_NUM  20000
#define KNOW_NUM  128
#define DIM       128
#define BATCH     8192
#define HIDDEN    512

typedef __attribute__((ext_vector_type(4))) float  f32x4;
typedef __attribute__((ext_vector_type(8))) __bf16 bf16x8;
typedef __attribute__((ext_vector_type(4))) __bf16 bf16x4;

__device__ __forceinline__ float sigmoidf_(float x) {
    return 1.0f / (1.0f + __expf(-x));
}
__device__ __forceinline__ float tanh_fast(float x) {
    return 1.0f - 2.0f / (__expf(2.0f * x) + 1.0f);
}

// async global->LDS, 16B per lane. LDS dest must be wave-uniform (HW adds lane*16).
__device__ __forceinline__ void gl2lds16(const void* g, void* l) {
    __builtin_amdgcn_global_load_lds(
        (const __attribute__((address_space(1))) void*)g,
        (__attribute__((address_space(3))) void*)l, 16, 0, 0);
}

// Swizzled byte offset inside a [64][64] bf16 tile (row stride 128B).
// 16B chunk index is XORed with (row&7): spreads the stride-128B column read
// across 8 bank groups (2 lanes/bank = free). Staging pre-swizzles the GLOBAL
// source so the LDS write stays linear (global_load_lds requirement).
__device__ __forceinline__ int swz(int row, int k) {
    return row * 128 + ((((k >> 3) ^ (row & 7)) << 4) | ((k & 7) << 1));
}

// Stage one 64x64 bf16 tile: global G[row0..+64)[k0..+64) (row stride ldk elems)
// -> lds_tile, 8 x 1KB instructions, 2 per wave.
__device__ __forceinline__ void stage_tile(const __bf16* __restrict__ G, size_t ldk,
                                           int row0, int k0, char* lds_tile,
                                           int wid, int lane) {
    #pragma unroll
    for (int ii = 0; ii < 2; ++ii) {
        int p    = wid + ii * 4;          // instruction index 0..7 (wave-uniform)
        int row  = p * 8 + (lane >> 3);   // tile row this lane covers
        int slot = lane & 7;              // 16B chunk within the row
        const __bf16* src = G + (size_t)(row0 + row) * ldk
                              + (size_t)(k0 + ((slot ^ (row & 7)) << 3));
        gl2lds16(src, lds_tile + p * 1024);
    }
}

__device__ __forceinline__ bf16x8 read_frag(const char* lds_tile, int row, int k) {
    return *reinterpret_cast<const bf16x8*>(lds_tile + swz(row, k));
}

__device__ __forceinline__ f32x4 mfma16(bf16x8 a, bf16x8 b, f32x4 c) {
    return __builtin_amdgcn_mfma_f32_16x16x32_bf16(a, b, c, 0, 0, 0);
}

// ---------------------------------------------------------------------------
// bf16 MFMA GEMM, block tile 64x64, 4 waves (2x2), wave tile 32x32, BK=64.
// B is stored transposed [N][K].
// DUAL=false: C = tanh(A@B^T + bias), bf16 out [M][N].
// DUAL=true : two A operands (A, A+8192*K), epilogue
//             state = bf16( kp * (sig(acc1+bstat) - sig(acc2+bkdiff)) ).
// ---------------------------------------------------------------------------
template<bool DUAL>
__global__ __launch_bounds__(256) void gemm_bf16(
    const __bf16* __restrict__ A, const __bf16* __restrict__ BT,
    const float* __restrict__ bias, __bf16* __restrict__ Cout,
    int M, int N, int K,
    const float* __restrict__ kp,
    const float* __restrict__ bstat, const float* __restrict__ bkdiff) {
    __shared__ char lds[3 * 8192];  // As | Bs | As2(optional)
    char* As  = lds;
    char* Bs  = lds + 8192;
    char* As2 = lds + 16384;

    const int t = threadIdx.x, lane = t & 63, wid = t >> 6;
    const int wr = wid >> 1, wc = wid & 1;
    const int m0 = blockIdx.x * 64, n0 = blockIdx.y * 64;

    f32x4 zero = {0.f, 0.f, 0.f, 0.f};
    f32x4 acc[2][2], acc2[2][2];
    #pragma unroll
    for (int i = 0; i < 2; ++i)
        #pragma unroll
        for (int j = 0; j < 2; ++j) { acc[i][j] = zero; acc2[i][j] = zero; }

    for (int k0 = 0; k0 < K; k0 += 64) {
        __syncthreads();   // previous iteration's frag reads complete
        stage_tile(A, K, m0, k0, As, wid, lane);
        if constexpr (DUAL) stage_tile(A + (size_t)8192 * K, K, m0, k0, As2, wid, lane);
        stage_tile(BT, K, n0, k0, Bs, wid, lane);
        __syncthreads();   // compiler drains vmcnt before barrier -> tiles ready

        #pragma unroll
        for (int ks = 0; ks < 2; ++ks) {
            const int kk = ks * 32 + (lane >> 4) * 8;
            bf16x8 a[2], b[2], a2[2];
            #pragma unroll
            for (int i = 0; i < 2; ++i)
                a[i] = read_frag(As, wr * 32 + i * 16 + (lane & 15), kk);
            #pragma unroll
            for (int j = 0; j < 2; ++j)
                b[j] = read_frag(Bs, wc * 32 + j * 16 + (lane & 15), kk);
            if constexpr (DUAL) {
                #pragma unroll
                for (int i = 0; i < 2; ++i)
                    a2[i] = read_frag(As2, wr * 32 + i * 16 + (lane & 15), kk);
            }
            #pragma unroll
            for (int i = 0; i < 2; ++i)
                #pragma unroll
                for (int j = 0; j < 2; ++j) {
                    acc[i][j] = mfma16(a[i], b[j], acc[i][j]);
                    if constexpr (DUAL) acc2[i][j] = mfma16(a2[i], b[j], acc2[i][j]);
                }
        }
    }

    // Epilogue. C/D frag: col = lane&15 (+16j), row = (lane>>4)*4 + reg (+16i).
    const int colb  = n0 + wc * 32 + (lane & 15);
    const int rowb  = m0 + wr * 32 + (lane >> 4) * 4;
    if constexpr (DUAL) {
        const float bs = bstat[0], bk = bkdiff[0];
        #pragma unroll
        for (int i = 0; i < 2; ++i)
            #pragma unroll
            for (int j = 0; j < 2; ++j)
                #pragma unroll
                for (int r = 0; r < 4; ++r) {
                    const int row = rowb + i * 16 + r;
                    const int c   = colb + j * 16;
                    float st = kp[(size_t)row * KNOW_NUM + c] *
                               (sigmoidf_(acc[i][j][r] + bs) - sigmoidf_(acc2[i][j][r] + bk));
                    Cout[(size_t)row * KNOW_NUM + c] = (__bf16)st;
                }
    } else {
        float bcol[2] = { bias[colb], bias[colb + 16] };
        #pragma unroll
        for (int i = 0; i < 2; ++i)
            #pragma unroll
            for (int j = 0; j < 2; ++j)
                #pragma unroll
                for (int r = 0; r < 4; ++r) {
                    float v = tanh_fast(acc[i][j][r] + bcol[j]);
                    Cout[(size_t)(rowb + i * 16 + r) * N + colb + j * 16] = (__bf16)v;
                }
    }
}

// ---------------------------------------------------------------------------
// Xg[16384][128] bf16: rows 0..8191 = z[sid]*w_stat, 8192.. = z[eid]*w_kdiff.
// 32 threads/row, 4 elems/thread; 524K threads hide the random-row latency.
// ---------------------------------------------------------------------------
__global__ void gather_kernel(const float* __restrict__ z,
                              const int* __restrict__ sid, const int* __restrict__ eid,
                              const float* __restrict__ w_stat, const float* __restrict__ w_kdiff,
                              __bf16* __restrict__ Xg) {
    int gid = blockIdx.x * 256 + threadIdx.x;
    int r   = gid >> 5;
    int c4  = (gid & 31) * 4;
    int zrow; const float* w;
    if (r < BATCH) { zrow = sid[r];          w = w_stat;  }
    else           { zrow = eid[r - BATCH];  w = w_kdiff; }
    float4 zv = *reinterpret_cast<const float4*>(z + (size_t)zrow * DIM + c4);
    float4 wv = *reinterpret_cast<const float4*>(w + c4);
    bf16x4 o;
    o[0] = (__bf16)(zv.x * wv.x);
    o[1] = (__bf16)(zv.y * wv.y);
    o[2] = (__bf16)(zv.z * wv.z);
    o[3] = (__bf16)(zv.w * wv.w);
    *reinterpret_cast<bf16x4*>(Xg + (size_t)r * DIM + c4) = o;
}

// ---------------------------------------------------------------------------
// prep: knowledge block -> bf16 (already [k][d] = B^T layout), W1/W2/W3 ->
// bf16 transposed [N][K]. Coalesced reads, scattered 2B writes (L2 absorbs).
// ---------------------------------------------------------------------------
__global__ void prep_kernel(const float* __restrict__ z,
                            const float* __restrict__ W1, const float* __restrict__ W2,
                            const float* __restrict__ W3,
                            __bf16* __restrict__ KB, __bf16* __restrict__ W1T,
                            __bf16* __restrict__ W2T, __bf16* __restrict__ W3T) {
    int i = blockIdx.x * 256 + threadIdx.x;
    if (i < KNOW_NUM * DIM) {
        KB[i] = (__bf16)z[(size_t)(STU_NUM + PROB_NUM) * DIM + i];
        return;
    }
    i -= KNOW_NUM * DIM;
    if (i < KNOW_NUM * HIDDEN) {            // W1 [128][512]
        int k = i >> 9, n = i & 511;
        W1T[(size_t)n * KNOW_NUM + k] = (__bf16)W1[i];
        return;
    }
    i -= KNOW_NUM * HIDDEN;
    if (i < HIDDEN * (HIDDEN / 2)) {        // W2 [512][256]
        int k = i >> 8, n = i & 255;
        W2T[(size_t)n * HIDDEN + k] = (__bf16)W2[i];
        return;
    }
    i -= HIDDEN * (HIDDEN / 2);
    if (i < (HIDDEN / 2) * (HIDDEN / 4)) {  // W3 [256][128]
        int k = i >> 7, n = i & 127;
        W3T[(size_t)n * (HIDDEN / 2) + k] = (__bf16)W3[i];
    }
}

// out[b] = sigmoid(dot(h3[b], W4) + b4). 16 lanes per row, shfl reduce.
__global__ void final_kernel(const __bf16* __restrict__ h3, const float* __restrict__ W4,
                             const float* __restrict__ b4, float* __restrict__ out) {
    int t = threadIdx.x, lane = t & 63, wid = t >> 6;
    int row = blockIdx.x * 16 + wid * 4 + (lane >> 4);
    int seg = (lane & 15) * 8;
    bf16x8 h = *reinterpret_cast<const bf16x8*>(h3 + (size_t)row * (HIDDEN / 4) + seg);
    float s = 0.f;
    #pragma unroll
    for (int j = 0; j < 8; ++j) s += (float)h[j] * W4[seg + j];
    #pragma unroll
    for (int off = 1; off < 16; off <<= 1) s += __shfl_xor(s, off);
    if ((lane & 15) == 0) out[row] = sigmoidf_(s + b4[0]);
}

extern "C" void kernel_launch(void* const* d_in, const int* in_sizes, int n_in,
                              void* d_out, int out_size, void* d_ws, size_t ws_size,
                              hipStream_t stream) {
    const float* z       = (const float*)d_in[0];
    const int*   sid     = (const int*)d_in[1];
    const int*   eid     = (const int*)d_in[2];
    const float* kp      = (const float*)d_in[3];
    const float* w_stat  = (const float*)d_in[4];
    const float* b_stat  = (const float*)d_in[5];
    const float* w_kdiff = (const float*)d_in[6];
    const float* b_kdiff = (const float*)d_in[7];
    const float* W1      = (const float*)d_in[8];
    const float* b1      = (const float*)d_in[9];
    const float* W2      = (const float*)d_in[10];
    const float* b2      = (const float*)d_in[11];
    const float* W3      = (const float*)d_in[12];
    const float* b3      = (const float*)d_in[13];
    const float* W4      = (const float*)d_in[14];
    const float* b4      = (const float*)d_in[15];
    float* out = (float*)d_out;

    // Workspace layout (bytes), ~20.5 MB total.
    char* ws = (char*)d_ws;
    __bf16* KB    = (__bf16*)(ws + 0);          //  32 KB [128][128]
    __bf16* W1T   = (__bf16*)(ws + 32768);      // 128 KB [512][128]
    __bf16* W2T   = (__bf16*)(ws + 163840);     // 256 KB [256][512]
    __bf16* W3T   = (__bf16*)(ws + 425984);     //  64 KB [128][256]
    __bf16* Xg    = (__bf16*)(ws + 524288);     //   4 MB [16384][128]
    __bf16* state = (__bf16*)(ws + 4718592);    //   2 MB [8192][128]
    __bf16* h1    = (__bf16*)(ws + 6815744);    //   8 MB [8192][512]
    __bf16* h2    = (__bf16*)(ws + 15204352);   //   4 MB [8192][256]
    __bf16* h3    = (__bf16*)(ws + 19398656);   //   2 MB [8192][128]

    // 1) weight/knowledge conversion+transpose (245,760 elements)
    hipLaunchKernelGGL(prep_kernel, dim3(960), dim3(256), 0, stream,
                       z, W1, W2, W3, KB, W1T, W2T, W3T);

    // 2) embedding gather+scale -> bf16 (latency hidden by 8192 waves)
    hipLaunchKernelGGL(gather_kernel, dim3(2 * BATCH * 32 / 256), dim3(256), 0, stream,
                       z, sid, eid, w_stat, w_kdiff, Xg);

    // 3) dual GEMM + fused sigmoid-diff combine:
    //    state = kp * (sig(Xs@KB^T+bs) - sig(Xk@KB^T+bk)), bf16 [8192][128]
    hipLaunchKernelGGL((gemm_bf16<true>), dim3(BATCH / 64, KNOW_NUM / 64), dim3(256), 0, stream,
                       Xg, KB, nullptr, state, BATCH, KNOW_NUM, DIM,
                       kp, b_stat, b_kdiff);

    // 4) h1 = tanh(state @ W1 + b1)   [8192 x 512], K=128
    hipLaunchKernelGGL((gemm_bf16<false>), dim3(BATCH / 64, HIDDEN / 64), dim3(256), 0, stream,
                       state, W1T, b1, h1, BATCH, HIDDEN, KNOW_NUM,
                       nullptr, nullptr, nullptr);

    // 5) h2 = tanh(h1 @ W2 + b2)      [8192 x 256], K=512
    hipLaunchKernelGGL((gemm_bf16<false>), dim3(BATCH / 64, (HIDDEN / 2) / 64), dim3(256), 0, stream,
                       h1, W2T, b2, h2, BATCH, HIDDEN / 2, HIDDEN,
                       nullptr, nullptr, nullptr);

    // 6) h3 = tanh(h2 @ W3 + b3)      [8192 x 128], K=256
    hipLaunchKernelGGL((gemm_bf16<false>), dim3(BATCH / 64, (HIDDEN / 4) / 64), dim3(256), 0, stream,
                       h2, W3T, b3, h3, BATCH, HIDDEN / 4, HIDDEN / 2,
                       nullptr, nullptr, nullptr);

    // 7) out = sigmoid(h3 @ W4 + b4)
    hipLaunchKernelGGL(final_kernel, dim3(BATCH / 16), dim3(256), 0, stream, h3, W4, b4, out);
}

// Round 3
// 33.586 us; speedup vs baseline: 4.0970x; 1.1775x over previous
//
#include <hip/hip_runtime.h>
#include <hip/hip_bf16.h>
#include <math.h>

#define STU_NUM   100000
#define PROB_NUM  20000
#define KNOW_NUM  128
#define DIM       128
#define BATCH     8192
#define HIDDEN    512

typedef __attribute__((ext_vector_type(4))) float  f32x4;
typedef __attribute__((ext_vector_type(8))) __bf16 bf16x8;

__device__ __forceinline__ float sigmoidf_(float x) { return 1.0f / (1.0f + __expf(-x)); }
__device__ __forceinline__ float tanh_fast(float x) { return 1.0f - 2.0f / (__expf(2.0f * x) + 1.0f); }

// async global->LDS, 16B/lane; LDS dest wave-uniform base (HW adds lane*16).
__device__ __forceinline__ void gl2lds16(const void* g, void* l) {
    __builtin_amdgcn_global_load_lds(
        (const __attribute__((address_space(1))) void*)g,
        (__attribute__((address_space(3))) void*)l, 16, 0, 0);
}

// Byte offset of element (row, kk) inside a [*][64] bf16 tile, 16B-chunk XOR swizzle:
// breaks the row-stride-128B bank alignment (T2). kk in [0,64).
__device__ __forceinline__ int swz(int row, int kk) {
    return row * 128 + ((((kk >> 3) ^ (row & 7)) << 4) | ((kk & 7) << 1));
}
__device__ __forceinline__ bf16x8 rfrag(const char* tile, int row, int kk) {
    return *reinterpret_cast<const bf16x8*>(tile + swz(row, kk));
}
__device__ __forceinline__ f32x4 mfma16(bf16x8 a, bf16x8 b, f32x4 c) {
    return __builtin_amdgcn_mfma_f32_16x16x32_bf16(a, b, c, 0, 0, 0);
}

// Stage a [128 n][64 k] bf16 tile (16KB) from row-major G (leading dim ldk) into buf.
// 16 x 1KB global_load_lds, 2 per wave (8 waves). Source pre-swizzled so the linear
// LDS write lands in swz() layout.
__device__ __forceinline__ void stageB(const __bf16* __restrict__ G, int ldk, int n0, int k0,
                                       char* buf, int wid, int lane) {
    #pragma unroll
    for (int ii = 0; ii < 2; ++ii) {
        int p    = wid * 2 + ii;          // 0..15
        int row  = p * 8 + (lane >> 3);   // n-row 0..127
        int slot = lane & 7;
        const __bf16* src = G + (size_t)(n0 + row) * ldk + k0 + ((slot ^ (row & 7)) << 3);
        gl2lds16(src, buf + p * 1024);
    }
}

// ---- LDS layout (bytes), 96KB total, phase-aliased ----
// GEMM1:  kbuf 0..32K | Xs 32K..40K | Xk 40K..48K | state 48K..56K (out)
// layers: wbuf0 0..16K | wbuf1 16K..32K | h2 32K..48K | state 48K..56K | h1 56K..88K | h3 88K..96K
#define L_WBUF0 0
#define L_WBUF1 16384
#define L_KBUF  0
#define L_XS    32768
#define L_XK    40960
#define L_H2    32768
#define L_STATE 49152
#define L_H1    57344
#define L_H3    90112
#define LDS_BYTES 98304

// One MLP layer: O = tanh(A @ WT^T + bias), M=32 rows, A/O in LDS A-layout
// ([32][64]-swz tiles, 4KB each, k-major). WT is [N][K] row-major bf16 in global.
// 8 waves: wm in {0,1} -> 16 rows, wn in {0..3} -> 32 cols of a 128-wide n-tile.
// T3/T4: double-buffered B staging with counted vmcnt(2) (2 loads in flight/wave),
// raw s_barrier pairs -- never drains the prefetch in the k-loop.
template<int N, int K>
__device__ __forceinline__ void layer(const __bf16* __restrict__ WT, const float* __restrict__ bias,
                                      const char* __restrict__ A, char* __restrict__ O,
                                      char* lds, int wid, int wm, int wn, int lane) {
    char* wb[2] = { lds + L_WBUF0, lds + L_WBUF1 };
    constexpr int NKT = K / 64;
    #pragma unroll 1
    for (int nt = 0; nt < N / 128; ++nt) {
        stageB(WT, K, nt * 128, 0, wb[0], wid, lane);
        f32x4 acc0 = {0.f, 0.f, 0.f, 0.f}, acc1 = {0.f, 0.f, 0.f, 0.f};
        #pragma unroll 1
        for (int kt = 0; kt < NKT; ++kt) {
            if (kt + 1 < NKT) {
                stageB(WT, K, nt * 128, (kt + 1) * 64, wb[(kt + 1) & 1], wid, lane);
                asm volatile("s_waitcnt vmcnt(2)" ::: "memory");   // tile kt landed, kt+1 in flight
            } else {
                asm volatile("s_waitcnt vmcnt(0)" ::: "memory");
            }
            __builtin_amdgcn_s_barrier();
            const char* cb = wb[kt & 1];
            __builtin_amdgcn_s_setprio(1);
            #pragma unroll
            for (int ks = 0; ks < 2; ++ks) {
                int kk = ks * 32 + (lane >> 4) * 8;
                bf16x8 a  = rfrag(A + kt * 4096, wm * 16 + (lane & 15), kk);
                bf16x8 b0 = rfrag(cb, wn * 32 + (lane & 15), kk);
                bf16x8 b1 = rfrag(cb, wn * 32 + 16 + (lane & 15), kk);
                acc0 = mfma16(a, b0, acc0);
                acc1 = mfma16(a, b1, acc1);
            }
            __builtin_amdgcn_s_setprio(0);
            __builtin_amdgcn_s_barrier();   // all waves done reading cb before it's restaged
        }
        // epilogue: bias + tanh -> O in A-layout (it's the next layer's K dimension)
        int colb = nt * 128 + wn * 32 + (lane & 15);
        int rowb = wm * 16 + (lane >> 4) * 4;
        float b0v = bias[colb], b1v = bias[colb + 16];
        #pragma unroll
        for (int r = 0; r < 4; ++r) {
            float v0 = tanh_fast(acc0[r] + b0v);
            float v1 = tanh_fast(acc1[r] + b1v);
            int row = rowb + r;
            int c0 = colb, c1 = colb + 16;
            *reinterpret_cast<__bf16*>(O + (c0 >> 6) * 4096 + swz(row, c0 & 63)) = (__bf16)v0;
            *reinterpret_cast<__bf16*>(O + (c1 >> 6) * 4096 + swz(row, c1 & 63)) = (__bf16)v1;
        }
    }
    __syncthreads();
}

// ---------------------------------------------------------------------------
// Fully fused: gather -> dual GEMM + sigmoid-diff -> 3 tanh layers -> final dot.
// 256 blocks x 32 batch rows, 512 threads (8 waves), all intermediates in LDS.
// ---------------------------------------------------------------------------
__global__ __launch_bounds__(512) void fused_kernel(
    const float* __restrict__ z, const int* __restrict__ sid, const int* __restrict__ eid,
    const float* __restrict__ kp, const float* __restrict__ bstat, const float* __restrict__ bkdiff,
    const float* __restrict__ w_stat, const float* __restrict__ w_kdiff,
    const __bf16* __restrict__ KBg, const __bf16* __restrict__ W1T,
    const __bf16* __restrict__ W2T, const __bf16* __restrict__ W3T,
    const float* __restrict__ b1, const float* __restrict__ b2, const float* __restrict__ b3,
    const float* __restrict__ W4, const float* __restrict__ b4,
    float* __restrict__ out) {
    __shared__ char lds[LDS_BYTES];
    const int t = threadIdx.x, lane = t & 63, wid = t >> 6;
    const int wm = wid >> 2, wn = wid & 3;
    const int rb0 = blockIdx.x * 32;

    // ---- phase 0: stage KB (B^T [128 n][128 k], 2 tiles) + gather Xs/Xk ----
    stageB(KBg, 128, 0, 0,  lds + L_KBUF,         wid, lane);
    stageB(KBg, 128, 0, 64, lds + L_KBUF + 16384, wid, lane);
    {
        int gr = t >> 3, row = gr & 31;          // 64 z-rows, 8 threads each
        bool ise = gr >= 32;
        int rb = rb0 + row;
        int zrow = ise ? eid[rb] : sid[rb];      // absolute row ids into z
        const float* w = ise ? w_kdiff : w_stat;
        char* Xb = lds + (ise ? L_XK : L_XS);
        int c0 = (t & 7) * 16;
        const float4* zp = reinterpret_cast<const float4*>(z + (size_t)zrow * DIM + c0);
        const float4* wp = reinterpret_cast<const float4*>(w + c0);
        #pragma unroll
        for (int q = 0; q < 2; ++q) {
            float4 za = zp[2 * q], zb = zp[2 * q + 1];
            float4 wa = wp[2 * q], wb2 = wp[2 * q + 1];
            bf16x8 o;
            o[0] = (__bf16)(za.x * wa.x);  o[1] = (__bf16)(za.y * wa.y);
            o[2] = (__bf16)(za.z * wa.z);  o[3] = (__bf16)(za.w * wa.w);
            o[4] = (__bf16)(zb.x * wb2.x); o[5] = (__bf16)(zb.y * wb2.y);
            o[6] = (__bf16)(zb.z * wb2.z); o[7] = (__bf16)(zb.w * wb2.w);
            int c = c0 + q * 8;
            *reinterpret_cast<bf16x8*>(Xb + (c >> 6) * 4096 + swz(row, c & 63)) = o;
        }
    }
    __syncthreads();   // drains vmcnt (KB staged) + lgkm (gather writes)

    // ---- phase 1: dual GEMM (Xs,Xk) @ KB^T, fused sigmoid-diff -> state ----
    f32x4 aS0 = {0.f,0.f,0.f,0.f}, aS1 = {0.f,0.f,0.f,0.f};
    f32x4 aK0 = {0.f,0.f,0.f,0.f}, aK1 = {0.f,0.f,0.f,0.f};
    __builtin_amdgcn_s_setprio(1);
    #pragma unroll
    for (int kt = 0; kt < 2; ++kt)
        #pragma unroll
        for (int ks = 0; ks < 2; ++ks) {
            int kk = ks * 32 + (lane >> 4) * 8;
            bf16x8 as = rfrag(lds + L_XS + kt * 4096, wm * 16 + (lane & 15), kk);
            bf16x8 ak = rfrag(lds + L_XK + kt * 4096, wm * 16 + (lane & 15), kk);
            bf16x8 b0 = rfrag(lds + L_KBUF + kt * 16384, wn * 32 + (lane & 15), kk);
            bf16x8 b1 = rfrag(lds + L_KBUF + kt * 16384, wn * 32 + 16 + (lane & 15), kk);
            aS0 = mfma16(as, b0, aS0); aS1 = mfma16(as, b1, aS1);
            aK0 = mfma16(ak, b0, aK0); aK1 = mfma16(ak, b1, aK1);
        }
    __builtin_amdgcn_s_setprio(0);
    {
        float bs = bstat[0], bk = bkdiff[0];
        int colb = wn * 32 + (lane & 15);
        int rowb = wm * 16 + (lane >> 4) * 4;
        #pragma unroll
        for (int r = 0; r < 4; ++r) {
            int row = rowb + r;
            size_t grow = rb0 + row;
            float s0 = kp[grow * KNOW_NUM + colb] *
                       (sigmoidf_(aS0[r] + bs) - sigmoidf_(aK0[r] + bk));
            float s1 = kp[grow * KNOW_NUM + colb + 16] *
                       (sigmoidf_(aS1[r] + bs) - sigmoidf_(aK1[r] + bk));
            int c1 = colb + 16;
            *reinterpret_cast<__bf16*>(lds + L_STATE + (colb >> 6) * 4096 + swz(row, colb & 63)) = (__bf16)s0;
            *reinterpret_cast<__bf16*>(lds + L_STATE + (c1   >> 6) * 4096 + swz(row, c1   & 63)) = (__bf16)s1;
        }
    }
    __syncthreads();   // state ready; kbuf/Xs/Xk now dead (aliased below)

    // ---- phases 2-4: MLP layers, weights streamed from L2 ----
    layer<HIDDEN,     DIM>       (W1T, b1, lds + L_STATE, lds + L_H1, lds, wid, wm, wn, lane);
    layer<HIDDEN / 2, HIDDEN>    (W2T, b2, lds + L_H1,    lds + L_H2, lds, wid, wm, wn, lane);
    layer<HIDDEN / 4, HIDDEN / 2>(W3T, b3, lds + L_H2,    lds + L_H3, lds, wid, wm, wn, lane);

    // ---- phase 5: out[rb] = sigmoid(dot(h3_row, W4) + b4), 16 lanes/row ----
    {
        int row  = t >> 4;           // 0..31
        int part = (t & 15) * 8;     // 0..120
        bf16x8 h = *reinterpret_cast<const bf16x8*>(lds + L_H3 + (part >> 6) * 4096 + swz(row, part & 63));
        float s = 0.f;
        #pragma unroll
        for (int j = 0; j < 8; ++j) s += (float)h[j] * W4[part + j];
        s += __shfl_xor(s, 1); s += __shfl_xor(s, 2);
        s += __shfl_xor(s, 4); s += __shfl_xor(s, 8);
        if ((t & 15) == 0) out[rb0 + row] = sigmoidf_(s + b4[0]);
    }
}

// ---------------------------------------------------------------------------
// prep: f32 -> bf16 weight reorg, write-coalesced (reads hit L2/L3).
// KB [128 k'][128 d] (knowledge block, already B^T), W1T/W2T/W3T as [N][K].
// ---------------------------------------------------------------------------
__global__ void prep_kernel(const float* __restrict__ z,
                            const float* __restrict__ W1, const float* __restrict__ W2,
                            const float* __restrict__ W3,
                            __bf16* __restrict__ KB, __bf16* __restrict__ W1T,
                            __bf16* __restrict__ W2T, __bf16* __restrict__ W3T) {
    int i = blockIdx.x * 256 + threadIdx.x;
    if (i < 16384) { KB[i] = (__bf16)z[(size_t)(STU_NUM + PROB_NUM) * DIM + i]; return; }
    i -= 16384;
    if (i < 65536) {   // W1T [512][128] <- W1 [128][512]
        int n = i >> 7, k = i & 127;
        W1T[i] = (__bf16)W1[(size_t)k * HIDDEN + n]; return;
    }
    i -= 65536;
    if (i < 131072) {  // W2T [256][512] <- W2 [512][256]
        int n = i >> 9, k = i & 511;
        W2T[i] = (__bf16)W2[(size_t)k * (HIDDEN / 2) + n]; return;
    }
    i -= 131072;
    if (i < 32768) {   // W3T [128][256] <- W3 [256][128]
        int n = i >> 8, k = i & 255;
        W3T[i] = (__bf16)W3[(size_t)k * (HIDDEN / 4) + n];
    }
}

extern "C" void kernel_launch(void* const* d_in, const int* in_sizes, int n_in,
                              void* d_out, int out_size, void* d_ws, size_t ws_size,
                              hipStream_t stream) {
    const float* z       = (const float*)d_in[0];
    const int*   sid     = (const int*)d_in[1];
    const int*   eid     = (const int*)d_in[2];
    const float* kp      = (const float*)d_in[3];
    const float* w_stat  = (const float*)d_in[4];
    const float* b_stat  = (const float*)d_in[5];
    const float* w_kdiff = (const float*)d_in[6];
    const float* b_kdiff = (const float*)d_in[7];
    const float* W1      = (const float*)d_in[8];
    const float* b1      = (const float*)d_in[9];
    const float* W2      = (const float*)d_in[10];
    const float* b2      = (const float*)d_in[11];
    const float* W3      = (const float*)d_in[12];
    const float* b3      = (const float*)d_in[13];
    const float* W4      = (const float*)d_in[14];
    const float* b4      = (const float*)d_in[15];
    float* out = (float*)d_out;

    // ws: converted weights only (480KB)
    char* ws = (char*)d_ws;
    __bf16* KB  = (__bf16*)(ws + 0);        //  32 KB [128][128]
    __bf16* W1T = (__bf16*)(ws + 32768);    // 128 KB [512][128]
    __bf16* W2T = (__bf16*)(ws + 163840);   // 256 KB [256][512]
    __bf16* W3T = (__bf16*)(ws + 425984);   //  64 KB [128][256]

    hipLaunchKernelGGL(prep_kernel, dim3(960), dim3(256), 0, stream,
                       z, W1, W2, W3, KB, W1T, W2T, W3T);

    hipLaunchKernelGGL(fused_kernel, dim3(BATCH / 32), dim3(512), 0, stream,
                       z, sid, eid, kp, b_stat, b_kdiff, w_stat, w_kdiff,
                       KB, W1T, W2T, W3T, b1, b2, b3, W4, b4, out);
}

// Round 4
// 31.767 us; speedup vs baseline: 4.3317x; 1.0573x over previous
//
#include <hip/hip_runtime.h>
#include <hip/hip_bf16.h>
#include <math.h>

#define STU_NUM   100000
#define PROB_NUM  20000
#define KNOW_NUM  128
#define DIM       128
#define BATCH     8192
#define HIDDEN    512

typedef __attribute__((ext_vector_type(4))) float  f32x4;
typedef __attribute__((ext_vector_type(8))) __bf16 bf16x8;

__device__ __forceinline__ float sigmoidf_(float x) { return 1.0f / (1.0f + __expf(-x)); }
__device__ __forceinline__ float tanh_fast(float x) { return 1.0f - 2.0f / (__expf(2.0f * x) + 1.0f); }

// Byte offset of element (row, kk) inside a [32][64] bf16 LDS tile (4KB),
// 16B-chunk XOR swizzle to break the row-stride-128B bank alignment (T2).
__device__ __forceinline__ int swz(int row, int kk) {
    return row * 128 + ((((kk >> 3) ^ (row & 7)) << 4) | ((kk & 7) << 1));
}
// Activation buffers are arrays of [32][64] tiles along K: tile = kk>>6.
__device__ __forceinline__ bf16x8 rfragK(const char* buf, int row, int kk) {
    return *reinterpret_cast<const bf16x8*>(buf + (kk >> 6) * 4096 + swz(row, kk & 63));
}
__device__ __forceinline__ void wput(char* buf, int row, int col, float v) {
    *reinterpret_cast<__bf16*>(buf + (col >> 6) * 4096 + swz(row, col & 63)) = (__bf16)v;
}
__device__ __forceinline__ f32x4 mfma16(bf16x8 a, bf16x8 b, f32x4 c) {
    return __builtin_amdgcn_mfma_f32_16x16x32_bf16(a, b, c, 0, 0, 0);
}

// ---------------------------------------------------------------------------
// One MLP layer, barrier-free k-loop. M=32 rows (LDS, swz tiles). WT [N][K]
// row-major bf16 in global (L2-resident). 8 waves; wave wid owns cols
// [wid*N/8, (wid+1)*N/8) -> CG = N/128 colgroups of 16. Weights stream
// global->registers (16B/lane), so no LDS staging, no s_barrier in the loop.
// ---------------------------------------------------------------------------
template<int N, int K>
__device__ __forceinline__ void layerG(const __bf16* __restrict__ WT,
                                       const float* __restrict__ bias,
                                       const char* __restrict__ A, char* __restrict__ O,
                                       int wid, int lane) {
    constexpr int CG = N / 128;
    const int l15 = lane & 15, lk = (lane >> 4) * 8;
    const int nb = wid * (N / 8);
    f32x4 acc[2][CG];
    #pragma unroll
    for (int i = 0; i < 2; ++i)
        #pragma unroll
        for (int c = 0; c < CG; ++c) acc[i][c] = (f32x4){0.f, 0.f, 0.f, 0.f};

    #pragma unroll
    for (int kt = 0; kt < K / 32; ++kt) {
        const int kk = kt * 32 + lk;
        bf16x8 a0 = rfragK(A, l15, kk);
        bf16x8 a1 = rfragK(A, 16 + l15, kk);
        #pragma unroll
        for (int c = 0; c < CG; ++c) {
            bf16x8 b = *reinterpret_cast<const bf16x8*>(WT + (size_t)(nb + c * 16 + l15) * K + kk);
            acc[0][c] = mfma16(a0, b, acc[0][c]);
            acc[1][c] = mfma16(a1, b, acc[1][c]);
        }
    }
    // epilogue: bias + tanh -> O (k-major swz tiles; it's the next layer's K dim)
    #pragma unroll
    for (int c = 0; c < CG; ++c) {
        const int col = nb + c * 16 + l15;
        const float bv = bias[col];
        #pragma unroll
        for (int i = 0; i < 2; ++i)
            #pragma unroll
            for (int r = 0; r < 4; ++r)
                wput(O, i * 16 + (lane >> 4) * 4 + r, col, tanh_fast(acc[i][c][r] + bv));
    }
}

// ---------------------------------------------------------------------------
// Fully fused, 256 blocks x 32 batch rows, 512 threads (8 waves).
// LDS (80KB): Xs 8K | Xk 8K | state 8K | h1 32K | h2 16K | h3 8K.
// Only 5 __syncthreads in the whole kernel; all weight streaming barrier-free.
// ---------------------------------------------------------------------------
__global__ __launch_bounds__(512) void fused_kernel(
    const float* __restrict__ z, const int* __restrict__ sid, const int* __restrict__ eid,
    const float* __restrict__ kp, const float* __restrict__ bstat, const float* __restrict__ bkdiff,
    const float* __restrict__ w_stat, const float* __restrict__ w_kdiff,
    const __bf16* __restrict__ KB, const __bf16* __restrict__ W1T,
    const __bf16* __restrict__ W2T, const __bf16* __restrict__ W3T,
    const float* __restrict__ b1, const float* __restrict__ b2, const float* __restrict__ b3,
    const float* __restrict__ W4, const float* __restrict__ b4,
    float* __restrict__ out) {
    __shared__ char lds[81920];
    char* Xs = lds;
    char* Xk = lds + 8192;
    char* st = lds + 16384;
    char* h1 = lds + 24576;
    char* h2 = lds + 57344;
    char* h3 = lds + 73728;

    const int t = threadIdx.x, lane = t & 63, wid = t >> 6;
    const int l15 = lane & 15, lk = (lane >> 4) * 8;
    const int rb0 = blockIdx.x * 32;
    const int colb = wid * 16 + l15;   // phase-1 / layer-3 column owned by this lane

    // ---- phase 0: gather Xs/Xk into LDS; prefetch KB b-frags + kp to regs ----
    {
        int gr = t >> 3, row = gr & 31;          // 64 z-rows, 8 threads each
        bool ise = gr >= 32;
        int zrow = ise ? eid[rb0 + row] : sid[rb0 + row];
        const float* w = ise ? w_kdiff : w_stat;
        char* Xb = ise ? Xk : Xs;
        int c0 = (t & 7) * 16;
        const float4* zp = reinterpret_cast<const float4*>(z + (size_t)zrow * DIM + c0);
        const float4* wp = reinterpret_cast<const float4*>(w + c0);
        #pragma unroll
        for (int q = 0; q < 2; ++q) {
            float4 za = zp[2 * q], zb = zp[2 * q + 1];
            float4 wa = wp[2 * q], wb = wp[2 * q + 1];
            bf16x8 o;
            o[0] = (__bf16)(za.x * wa.x);  o[1] = (__bf16)(za.y * wa.y);
            o[2] = (__bf16)(za.z * wa.z);  o[3] = (__bf16)(za.w * wa.w);
            o[4] = (__bf16)(zb.x * wb.x);  o[5] = (__bf16)(zb.y * wb.y);
            o[6] = (__bf16)(zb.z * wb.z);  o[7] = (__bf16)(zb.w * wb.w);
            int c = c0 + q * 8;
            *reinterpret_cast<bf16x8*>(Xb + (c >> 6) * 4096 + swz(row, c & 63)) = o;
        }
    }
    bf16x8 kbf[4];
    #pragma unroll
    for (int kt = 0; kt < 4; ++kt)
        kbf[kt] = *reinterpret_cast<const bf16x8*>(KB + (size_t)colb * DIM + kt * 32 + lk);
    float kpv[2][4];
    #pragma unroll
    for (int i = 0; i < 2; ++i)
        #pragma unroll
        for (int r = 0; r < 4; ++r)
            kpv[i][r] = kp[(size_t)(rb0 + i * 16 + (lane >> 4) * 4 + r) * KNOW_NUM + colb];
    __syncthreads();

    // ---- phase 1: dual GEMM (Xs,Xk)@KB^T + sigmoid-diff -> state ----
    {
        f32x4 aS[2], aK[2];
        #pragma unroll
        for (int i = 0; i < 2; ++i) { aS[i] = (f32x4){0,0,0,0}; aK[i] = (f32x4){0,0,0,0}; }
        #pragma unroll
        for (int kt = 0; kt < 4; ++kt) {
            const int kk = kt * 32 + lk;
            bf16x8 s0 = rfragK(Xs, l15, kk), s1 = rfragK(Xs, 16 + l15, kk);
            bf16x8 q0 = rfragK(Xk, l15, kk), q1 = rfragK(Xk, 16 + l15, kk);
            aS[0] = mfma16(s0, kbf[kt], aS[0]);
            aS[1] = mfma16(s1, kbf[kt], aS[1]);
            aK[0] = mfma16(q0, kbf[kt], aK[0]);
            aK[1] = mfma16(q1, kbf[kt], aK[1]);
        }
        const float bs = bstat[0], bk = bkdiff[0];
        #pragma unroll
        for (int i = 0; i < 2; ++i)
            #pragma unroll
            for (int r = 0; r < 4; ++r) {
                float v = kpv[i][r] * (sigmoidf_(aS[i][r] + bs) - sigmoidf_(aK[i][r] + bk));
                wput(st, i * 16 + (lane >> 4) * 4 + r, colb, v);
            }
    }
    __syncthreads();

    // ---- phases 2-4: MLP, weights global->reg, barrier-free k-loops ----
    layerG<HIDDEN,     DIM>       (W1T, b1, st, h1, wid, lane);
    __syncthreads();
    layerG<HIDDEN / 2, HIDDEN>    (W2T, b2, h1, h2, wid, lane);
    __syncthreads();
    layerG<HIDDEN / 4, HIDDEN / 2>(W3T, b3, h2, h3, wid, lane);
    __syncthreads();

    // ---- phase 5: out = sigmoid(dot(h3_row, W4) + b4), 16 lanes/row ----
    {
        int row  = t >> 4;           // 0..31
        int part = (t & 15) * 8;     // 0..120
        bf16x8 h = rfragK(h3, row, part);
        float s = 0.f;
        #pragma unroll
        for (int j = 0; j < 8; ++j) s += (float)h[j] * W4[part + j];
        s += __shfl_xor(s, 1); s += __shfl_xor(s, 2);
        s += __shfl_xor(s, 4); s += __shfl_xor(s, 8);
        if ((t & 15) == 0) out[rb0 + row] = sigmoidf_(s + b4[0]);
    }
}

// ---------------------------------------------------------------------------
// prep: f32 -> bf16 weight reorg (reads L2-resident after first touch,
// writes coalesced). KB [128 k'][128 d] (= B^T already), W1T/W2T/W3T [N][K].
// ---------------------------------------------------------------------------
__global__ void prep_kernel(const float* __restrict__ z,
                            const float* __restrict__ W1, const float* __restrict__ W2,
                            const float* __restrict__ W3,
                            __bf16* __restrict__ KB, __bf16* __restrict__ W1T,
                            __bf16* __restrict__ W2T, __bf16* __restrict__ W3T) {
    int i = blockIdx.x * 256 + threadIdx.x;
    if (i < 16384) { KB[i] = (__bf16)z[(size_t)(STU_NUM + PROB_NUM) * DIM + i]; return; }
    i -= 16384;
    if (i < 65536) {   // W1T [512][128] <- W1 [128][512]
        int n = i >> 7, k = i & 127;
        W1T[i] = (__bf16)W1[(size_t)k * HIDDEN + n]; return;
    }
    i -= 65536;
    if (i < 131072) {  // W2T [256][512] <- W2 [512][256]
        int n = i >> 9, k = i & 511;
        W2T[i] = (__bf16)W2[(size_t)k * (HIDDEN / 2) + n]; return;
    }
    i -= 131072;
    if (i < 32768) {   // W3T [128][256] <- W3 [256][128]
        int n = i >> 8, k = i & 255;
        W3T[i] = (__bf16)W3[(size_t)k * (HIDDEN / 4) + n];
    }
}

extern "C" void kernel_launch(void* const* d_in, const int* in_sizes, int n_in,
                              void* d_out, int out_size, void* d_ws, size_t ws_size,
                              hipStream_t stream) {
    const float* z       = (const float*)d_in[0];
    const int*   sid     = (const int*)d_in[1];
    const int*   eid     = (const int*)d_in[2];
    const float* kp      = (const float*)d_in[3];
    const float* w_stat  = (const float*)d_in[4];
    const float* b_stat  = (const float*)d_in[5];
    const float* w_kdiff = (const float*)d_in[6];
    const float* b_kdiff = (const float*)d_in[7];
    const float* W1      = (const float*)d_in[8];
    const float* b1      = (const float*)d_in[9];
    const float* W2      = (const float*)d_in[10];
    const float* b2      = (const float*)d_in[11];
    const float* W3      = (const float*)d_in[12];
    const float* b3      = (const float*)d_in[13];
    const float* W4      = (const float*)d_in[14];
    const float* b4      = (const float*)d_in[15];
    float* out = (float*)d_out;

    char* ws = (char*)d_ws;
    __bf16* KB  = (__bf16*)(ws + 0);        //  32 KB [128][128]
    __bf16* W1T = (__bf16*)(ws + 32768);    // 128 KB [512][128]
    __bf16* W2T = (__bf16*)(ws + 163840);   // 256 KB [256][512]
    __bf16* W3T = (__bf16*)(ws + 425984);   //  64 KB [128][256]

    hipLaunchKernelGGL(prep_kernel, dim3(960), dim3(256), 0, stream,
                       z, W1, W2, W3, KB, W1T, W2T, W3T);

    hipLaunchKernelGGL(fused_kernel, dim3(BATCH / 32), dim3(512), 0, stream,
                       z, sid, eid, kp, b_stat, b_kdiff, w_stat, w_kdiff,
                       KB, W1T, W2T, W3T, b1, b2, b3, W4, b4, out);
}